// Round 15
// baseline (704.741 us; speedup 1.0000x reference)
//
#include <hip/hip_runtime.h>

// ResidualSimVQ eval forward — R15: R13 (best, 530us) + two diets:
// (1) epilogue computes z_q in-place in the LDS tile (tile holds z untouched
//     through the barrier-free main loop since Wn/CB/qf are all global) —
//     eliminates the second 64 MB z read;
// (2) reduced p hoisted to SGPRs via readfirstlane (butterfly leaves
//     bit-identical values on all lanes; v_fma takes 1 SGPR operand) —
//     frees ~36 VGPRs in the hot phase-2 loop.
// Structure identical to R13: barrier-free 9-stage loop, 4 rows/wave,
// launch_bounds(256,2) (VGPR-cap law 256/min_waves: only arg 2 fits the f64
// res chain; arg 3 caps 84 -> spill, arg 4 caps 64 -> spill), global
// L1-resident padded f32 Wn, f32 scoring + exact-f64 global fallback
// (gap < 0.015), f64 res chain (correctness: keeps res-vs-reference
// divergence ~1e-7 << expected min decision gap ~6e-5), f32 rotation
// scalars, nt hints on streaming z / z_q.  R14 lesson: per-stage LDS
// staging barriers cost more than L1 thrash — barrier-free wins.
// commit is wave-uniform -> lane 0's copy IS the wave total (no reduction).
// WRITE_SIZE ~67 MB is the no-spill health metric.

#define NB  16
#define DD  512
#define TT  2048
#define NCB 9
#define CS  1024
#define CD  8
#define KK  9    // CD + 1: slot 8 is the bias b
#define KP  12   // padded f32 row stride (48 B, 16B-aligned rows)
#define NBLK (NB * (TT / 16))   // 2048 k_main blocks
#define GAPTHR 0.015f

#define WS_WN_OFF  65536                                 // f64 [Wn|b], d-major [i][d][9] (fallback)
#define WS_WNF_OFF (WS_WN_OFF  + (size_t)NCB*DD*KK*8)    // f32 [Wn|b,pad], [i][d][12]
#define WS_Q_OFF   (WS_WNF_OFF + (size_t)NCB*DD*KP*4)    // f64 ||implicit||^2
#define WS_QF_OFF  (WS_Q_OFF   + (size_t)NCB*CS*8)       // f32 0.5*||implicit||^2

typedef float vf4 __attribute__((ext_vector_type(4)));   // clang vector for nontemporal builtins

__device__ __forceinline__ float rfl_f32(float x) {
  return __builtin_bit_cast(float, __builtin_amdgcn_readfirstlane(__builtin_bit_cast(int, x)));
}

__global__ void k_wn(const float* __restrict__ V, const float* __restrict__ g,
                     const float* __restrict__ bp, double* __restrict__ wn,
                     float* __restrict__ wnf) {
  int gid = blockIdx.x * 256 + threadIdx.x;
  if (gid >= NCB * DD) return;
  int i = gid / DD, d = gid % DD;
  const float* vp = V + (size_t)gid * CD;
  double v[CD], s = 0.0;
#pragma unroll
  for (int k = 0; k < CD; k++) { v[k] = (double)vp[k]; s = fma(v[k], v[k], s); }
  double den = fmax(sqrt(s), 1e-12);
  double gg = (double)g[gid];
  double* row = wn + ((size_t)i * DD + d) * KK;
  float* frow = wnf + ((size_t)i * DD + d) * KP;
#pragma unroll
  for (int k = 0; k < CD; k++) {
    double wv = gg * v[k] / den;
    row[k] = wv;
    frow[k] = (float)wv;
  }
  row[CD] = (double)bp[gid];
  frow[CD] = bp[gid];
  frow[9] = 0.0f; frow[10] = 0.0f; frow[11] = 0.0f;
}

__global__ void k_q(const float* __restrict__ CBp, const float* __restrict__ bp,
                    const double* __restrict__ wn,
                    double* __restrict__ q, float* __restrict__ qf) {
  int wid = blockIdx.x * 4 + (threadIdx.x >> 6);
  int lane = threadIdx.x & 63;
  int i = wid / CS, c = wid % CS;
  const float* cb = CBp + (size_t)(i * CS + c) * CD;
  double cbv[CD];
#pragma unroll
  for (int k = 0; k < CD; k++) cbv[k] = (double)cb[k];
  const double* wnp = wn + (size_t)i * DD * KK;
  const float* bb = bp + (size_t)i * DD;
  double acc = 0.0;
#pragma unroll
  for (int j = 0; j < 8; j++) {
    int d = j * 64 + lane;
    double imp = (double)bb[d];
#pragma unroll
    for (int k = 0; k < CD; k++) imp = fma(cbv[k], wnp[(size_t)d * KK + k], imp);
    acc = fma(imp, imp, acc);
  }
#pragma unroll
  for (int o = 32; o; o >>= 1) acc += __shfl_xor(acc, o, 64);
  if (lane == 0) { q[wid] = acc; qf[wid] = (float)(0.5 * acc); }
}

__launch_bounds__(256, 2)
__global__ void k_main(const float* __restrict__ z, const float* __restrict__ CBp,
                       const double* __restrict__ wn, const float* __restrict__ wnf,
                       const double* __restrict__ qtab, const float* __restrict__ qftab,
                       float* __restrict__ out_zq, float* __restrict__ out_codes,
                       double* __restrict__ partials) {
  __shared__ __align__(16) float tile[DD * 17];   // 34816 B — holds z all kernel
  __shared__ double cbuf[4];

  const int tid = threadIdx.x, lane = tid & 63, w = tid >> 6;
  const int bb = blockIdx.x >> 7, tg = blockIdx.x & 127;
  const int t0 = tg * 16;
  const float* zb = z + (size_t)bb * DD * TT + t0;

  // ---- prologue: stage z (non-temporal, single read), transpose in LDS ----
#pragma unroll
  for (int m = 0; m < 8; m++) {
    int F = tid + m * 256, d = F >> 2, qq = F & 3;
    const vf4 v = __builtin_nontemporal_load((const vf4*)(zb + (size_t)d * TT + qq * 4));
    tile[d * 17 + qq * 4 + 0] = v.x; tile[d * 17 + qq * 4 + 1] = v.y;
    tile[d * 17 + qq * 4 + 2] = v.z; tile[d * 17 + qq * 4 + 3] = v.w;
  }
  __syncthreads();

  double res[4][8], ns2[4];
#pragma unroll
  for (int r = 0; r < 4; r++) {
    double s = 0.0;
#pragma unroll
    for (int j = 0; j < 8; j++) {
      res[r][j] = (double)tile[(j * 64 + lane) * 17 + (w * 4 + r)];
      s = fma(res[r][j], res[r][j], s);
    }
    ns2[r] = s;
  }
#pragma unroll
  for (int o = 32; o; o >>= 1)
#pragma unroll
    for (int r = 0; r < 4; r++) ns2[r] += __shfl_xor(ns2[r], o, 64);

  double commit = 0.0;

  for (int i = 0; i < NCB; i++) {
    const float* wfp = wnf + (size_t)i * DD * KP;
    const float* cbbase = CBp + (size_t)i * CS * CD;
    const float* qfb = qftab + i * CS;
    const double* qb = qtab + i * CS;

    // ---- phase 1: pf[r][k] = -(res . [Wn|b]) in f32, one pass, 4 rows ----
    float pf[4][KK];
#pragma unroll
    for (int r = 0; r < 4; r++)
#pragma unroll
      for (int k = 0; k < KK; k++) pf[r][k] = 0.0f;
#pragma unroll
    for (int j = 0; j < 8; j++) {
      const float* row = wfp + (size_t)(j * 64 + lane) * KP;
      const float4 w0 = *(const float4*)(row);
      const float4 w1 = *(const float4*)(row + 4);
      const float  w8 = row[8];
      float rv[4];
#pragma unroll
      for (int r = 0; r < 4; r++) rv[r] = -(float)res[r][j];
#pragma unroll
      for (int r = 0; r < 4; r++) {
        pf[r][0] = fmaf(rv[r], w0.x, pf[r][0]);
        pf[r][1] = fmaf(rv[r], w0.y, pf[r][1]);
        pf[r][2] = fmaf(rv[r], w0.z, pf[r][2]);
        pf[r][3] = fmaf(rv[r], w0.w, pf[r][3]);
        pf[r][4] = fmaf(rv[r], w1.x, pf[r][4]);
        pf[r][5] = fmaf(rv[r], w1.y, pf[r][5]);
        pf[r][6] = fmaf(rv[r], w1.z, pf[r][6]);
        pf[r][7] = fmaf(rv[r], w1.w, pf[r][7]);
        pf[r][8] = fmaf(rv[r], w8,   pf[r][8]);
      }
    }
#pragma unroll
    for (int o = 32; o; o >>= 1)
#pragma unroll
      for (int r = 0; r < 4; r++)
#pragma unroll
        for (int k = 0; k < KK; k++) pf[r][k] += __shfl_xor(pf[r][k], o, 64);
    // butterfly leaves bit-identical values on all lanes (f32 add is
    // commutative) -> hoist to SGPRs: frees ~36 VGPRs; v_fma takes 1 SGPR.
#pragma unroll
    for (int r = 0; r < 4; r++)
#pragma unroll
      for (int k = 0; k < KK; k++) pf[r][k] = rfl_f32(pf[r][k]);

    // ---- phase 2: f32 argmin, one CB sweep, split even/odd chains ----
    float s1a[4], s2a[4], s1b[4], s2b[4];
    int   c1a[4], c1b[4];
#pragma unroll
    for (int r = 0; r < 4; r++) {
      s1a[r] = s2a[r] = s1b[r] = s2b[r] = 3.4e38f;
      c1a[r] = c1b[r] = 0;
    }
#pragma unroll 4
    for (int m = 0; m < 16; m += 2) {
#pragma unroll
      for (int h = 0; h < 2; h++) {
        int c = (m + h) * 64 + lane;
        const float4 c0 = *(const float4*)(cbbase + (size_t)c * CD);
        const float4 cx = *(const float4*)(cbbase + (size_t)c * CD + 4);
        float qv = qfb[c];
#pragma unroll
        for (int r = 0; r < 4; r++) {
          float s = qv;
          s = fmaf(c0.x, pf[r][0], s); s = fmaf(c0.y, pf[r][1], s);
          s = fmaf(c0.z, pf[r][2], s); s = fmaf(c0.w, pf[r][3], s);
          s = fmaf(cx.x, pf[r][4], s); s = fmaf(cx.y, pf[r][5], s);
          s = fmaf(cx.z, pf[r][6], s); s = fmaf(cx.w, pf[r][7], s);
          if (h == 0) {
            if (s < s1a[r]) { s2a[r] = s1a[r]; s1a[r] = s; c1a[r] = c; }
            else            { s2a[r] = fminf(s2a[r], s); }
          } else {
            if (s < s1b[r]) { s2b[r] = s1b[r]; s1b[r] = s; c1b[r] = c; }
            else            { s2b[r] = fminf(s2b[r], s); }
          }
        }
      }
    }
    float s1[4], s2[4]; int c1[4];
#pragma unroll
    for (int r = 0; r < 4; r++) {
      if (s1a[r] < s1b[r] || (s1a[r] == s1b[r] && c1a[r] < c1b[r])) {
        s1[r] = s1a[r]; c1[r] = c1a[r]; s2[r] = fminf(s2a[r], s1b[r]);
      } else {
        s1[r] = s1b[r]; c1[r] = c1b[r]; s2[r] = fminf(s2b[r], s1a[r]);
      }
    }
#pragma unroll
    for (int o = 32; o; o >>= 1) {
#pragma unroll
      for (int r = 0; r < 4; r++) {
        float os1 = __shfl_xor(s1[r], o, 64);
        int   oc1 = __shfl_xor(c1[r], o, 64);
        float os2 = __shfl_xor(s2[r], o, 64);
        float hi = fmaxf(s1[r], os1);
        s2[r] = fminf(fminf(s2[r], os2), hi);
        if (os1 < s1[r] || (os1 == s1[r] && oc1 < c1[r])) { s1[r] = os1; c1[r] = oc1; }
      }
    }

    // ---- per-row: rare exact-f64 fallback (global f64 Wn), scalars ----
    double Ap[4], Cm[4];
    float cbf[4][8];
#pragma unroll
    for (int r = 0; r < 4; r++) {
      if (s2[r] - s1[r] < GAPTHR) {   // wave-uniform, rare
        double pd[KK];
#pragma unroll
        for (int k = 0; k < KK; k++) pd[k] = 0.0;
#pragma unroll
        for (int j = 0; j < 8; j++) {
          const double* wrow = wn + ((size_t)i * DD + j * 64 + lane) * KK;
          double rv = res[r][j];
#pragma unroll
          for (int k = 0; k < KK; k++) pd[k] = fma(rv, wrow[k], pd[k]);
        }
#pragma unroll
        for (int o = 32; o; o >>= 1)
#pragma unroll
          for (int k = 0; k < KK; k++) pd[k] += __shfl_xor(pd[k], o, 64);
        double pm2[8];
#pragma unroll
        for (int k = 0; k < 8; k++) pm2[k] = -2.0 * pd[k];
        double bs = 1e300; int bc = 0;
#pragma unroll 4
        for (int m = 0; m < 16; m++) {
          int c = m * 64 + lane;
          const float* cb2 = cbbase + (size_t)c * CD;
          double s = qb[c];
#pragma unroll
          for (int k = 0; k < 8; k++) s = fma((double)cb2[k], pm2[k], s);
          if (s < bs) { bs = s; bc = c; }
        }
#pragma unroll
        for (int o = 32; o; o >>= 1) {
          double obs = __shfl_xor(bs, o, 64);
          int    obc = __shfl_xor(bc, o, 64);
          if (obs < bs || (obs == bs && obc < bc)) { bs = obs; bc = obc; }
        }
        c1[r] = bc;
      }
      int cu = __builtin_amdgcn_readfirstlane(c1[r]);
      const float* cbr = cbbase + (size_t)cu * CD;
      double pzn = (double)pf[r][8];
#pragma unroll
      for (int k = 0; k < 8; k++) {
        float cf = cbr[k];
        cbf[r][k] = cf;
        pzn = fma((double)cf, (double)pf[r][k], pzn);
      }
      double pz = -pzn;
      double nt2 = qb[cu];
      double n2 = ns2[r];
      // rotation scalars in f32 (A/C need only ~1e-7 rel; decisions already made)
      float n2f = (float)n2, nt2f = (float)nt2, pzf = (float)pz;
      float rnsf = (n2f  > 1e-12f) ? rsqrtf(n2f)  : 1e6f;
      float rntf = (nt2f > 1e-12f) ? rsqrtf(nt2f) : 1e6f;
      float sntf = nt2f * rntf;               // sqrt(nt2)
      float wn2f = n2f * rnsf * rnsf + 2.0f * pzf * rnsf * rntf + nt2f * rntf * rntf;
      float rdwf = (wn2f > 1e-12f) ? rsqrtf(wn2f) : 1e6f;
      float euf = n2f * rnsf;
      float ewf = (n2f * rnsf + pzf * rntf) * rdwf;
      float scalef = sntf * rnsf;
      float Af = scalef * (1.0f - 2.0f * ewf * rdwf * rnsf);
      float Cf = scalef * rntf * 2.0f * (euf - ewf * rdwf);
      commit += n2 - 2.0 * pz + nt2;
      double ap = 1.0 - (double)Af;
      double C  = (double)Cf;
      Ap[r] = ap; Cm[r] = C;
      ns2[r] = ap * ap * n2 - 2.0 * ap * C * pz + C * C * nt2;
      if (lane == 0)
        out_codes[((size_t)bb * NCB + i) * TT + t0 + w * 4 + r] = (float)cu;
    }

    // ---- phase 3: res' = Ap*res - Cm*(b + Wn.cb), f32 imp, one pass ----
#pragma unroll
    for (int j = 0; j < 8; j++) {
      const float* row = wfp + (size_t)(j * 64 + lane) * KP;
      const float4 w0 = *(const float4*)(row);
      const float4 w1 = *(const float4*)(row + 4);
      const float  w8 = row[8];
#pragma unroll
      for (int r = 0; r < 4; r++) {
        float impf = w8;
        impf = fmaf(cbf[r][0], w0.x, impf);
        impf = fmaf(cbf[r][1], w0.y, impf);
        impf = fmaf(cbf[r][2], w0.z, impf);
        impf = fmaf(cbf[r][3], w0.w, impf);
        impf = fmaf(cbf[r][4], w1.x, impf);
        impf = fmaf(cbf[r][5], w1.y, impf);
        impf = fmaf(cbf[r][6], w1.z, impf);
        impf = fmaf(cbf[r][7], w1.w, impf);
        res[r][j] = Ap[r] * res[r][j] - Cm[r] * (double)impf;
      }
    }
  }

  // ---- commit: wave-uniform already; lane 0 holds the wave total ----
  if (lane == 0) cbuf[w] = commit;

  // ---- z_q = z - res : tile STILL holds z (untouched by main loop).
  //      Each thread updates exactly the slots it alone read at res-init
  //      (unique ownership -> no race); then one barrier, then store. ----
#pragma unroll
  for (int r = 0; r < 4; r++)
#pragma unroll
    for (int j = 0; j < 8; j++) {
      int idx = (j * 64 + lane) * 17 + (w * 4 + r);
      tile[idx] = tile[idx] - (float)res[r][j];
    }
  __syncthreads();   // all slots updated; covers cbuf too
#pragma unroll
  for (int m = 0; m < 8; m++) {
    int F = tid + m * 256, d = F >> 2, qq = F & 3;
    vf4 o;
    o.x = tile[d * 17 + qq * 4 + 0];
    o.y = tile[d * 17 + qq * 4 + 1];
    o.z = tile[d * 17 + qq * 4 + 2];
    o.w = tile[d * 17 + qq * 4 + 3];
    __builtin_nontemporal_store(o, (vf4*)(out_zq + ((size_t)bb * DD + d) * TT + t0 + qq * 4));
  }
  if (tid == 0)
    partials[blockIdx.x] = cbuf[0] + cbuf[1] + cbuf[2] + cbuf[3];
}

__global__ void k_fin(const double* __restrict__ partials, float* __restrict__ outc) {
  __shared__ double sb[4];
  int tid = threadIdx.x, lane = tid & 63, w = tid >> 6;
  double s = 0.0;
#pragma unroll
  for (int m = 0; m < NBLK / 256; m++) s += partials[tid + m * 256];
#pragma unroll
  for (int o = 32; o; o >>= 1) s += __shfl_xor(s, o, 64);
  if (lane == 0) sb[w] = s;
  __syncthreads();
  if (tid == 0) {
    double tot = sb[0] + sb[1] + sb[2] + sb[3];
    outc[0] = (float)(tot * 1.25 / (double)((size_t)NB * TT * DD));
  }
}

extern "C" void kernel_launch(void* const* d_in, const int* in_sizes, int n_in,
                              void* d_out, int out_size, void* d_ws, size_t ws_size,
                              hipStream_t stream) {
  const float* z  = (const float*)d_in[0];
  const float* V  = (const float*)d_in[1];
  const float* g  = (const float*)d_in[2];
  const float* b  = (const float*)d_in[3];
  const float* CB = (const float*)d_in[4];
  float* out = (float*)d_out;

  double* parts = (double*)d_ws;
  double* wn  = (double*)((char*)d_ws + WS_WN_OFF);
  float*  wnf = (float*)((char*)d_ws + WS_WNF_OFF);
  double* q   = (double*)((char*)d_ws + WS_Q_OFF);
  float*  qf  = (float*)((char*)d_ws + WS_QF_OFF);

  hipLaunchKernelGGL(k_wn, dim3((NCB * DD + 255) / 256), dim3(256), 0, stream,
                     V, g, b, wn, wnf);
  hipLaunchKernelGGL(k_q, dim3((NCB * CS) / 4), dim3(256), 0, stream, CB, b, wn, q, qf);
  hipLaunchKernelGGL(k_main, dim3(NBLK), dim3(256), 0, stream,
                     z, CB, wn, wnf, q, qf,
                     out, out + (size_t)NB * DD * TT, parts);
  hipLaunchKernelGGL(k_fin, dim3(1), dim3(256), 0, stream,
                     parts, out + (size_t)NB * DD * TT + (size_t)NB * NCB * TT);
}

// Round 16
// 515.725 us; speedup vs baseline: 1.3665x; 1.3665x over previous
//
#include <hip/hip_runtime.h>

// ResidualSimVQ eval forward — R16: R13 (best, 530us) + ONLY the in-place
// epilogue from R15 (z_q computed in the LDS tile that still holds z after
// the barrier-free main loop; unique slot ownership -> one barrier).  The
// readfirstlane hoist (R15's other half) is DROPPED: 36 v_readfirstlane per
// stage created VALU->SALU hazard chains (VALUBusy 59->46, dur +33%).
// Structure: barrier-free 9-stage loop, 4 rows/wave, launch_bounds(256,2)
// (VGPR-cap law 256/min_waves: only arg 2 fits the f64 res chain), global
// L1-resident padded f32 Wn, f32 scoring + exact-f64 global fallback
// (gap < 0.015), f64 res chain, f32 rotation scalars, nt hints on z/z_q.
// Refuted ledger: R8/R9 occupancy raise (spill), R11 pk-f32 (stall),
// R14 LDS tables (barrier convoy), R15 SGPR hoist (hazards).
// commit is wave-uniform -> lane 0's copy IS the wave total (no reduction).
// WRITE_SIZE ~67 MB is the no-spill health metric.

#define NB  16
#define DD  512
#define TT  2048
#define NCB 9
#define CS  1024
#define CD  8
#define KK  9    // CD + 1: slot 8 is the bias b
#define KP  12   // padded f32 row stride (48 B, 16B-aligned rows)
#define NBLK (NB * (TT / 16))   // 2048 k_main blocks
#define GAPTHR 0.015f

#define WS_WN_OFF  65536                                 // f64 [Wn|b], d-major [i][d][9] (fallback)
#define WS_WNF_OFF (WS_WN_OFF  + (size_t)NCB*DD*KK*8)    // f32 [Wn|b,pad], [i][d][12]
#define WS_Q_OFF   (WS_WNF_OFF + (size_t)NCB*DD*KP*4)    // f64 ||implicit||^2
#define WS_QF_OFF  (WS_Q_OFF   + (size_t)NCB*CS*8)       // f32 0.5*||implicit||^2

typedef float vf4 __attribute__((ext_vector_type(4)));   // clang vector for nontemporal builtins

__global__ void k_wn(const float* __restrict__ V, const float* __restrict__ g,
                     const float* __restrict__ bp, double* __restrict__ wn,
                     float* __restrict__ wnf) {
  int gid = blockIdx.x * 256 + threadIdx.x;
  if (gid >= NCB * DD) return;
  int i = gid / DD, d = gid % DD;
  const float* vp = V + (size_t)gid * CD;
  double v[CD], s = 0.0;
#pragma unroll
  for (int k = 0; k < CD; k++) { v[k] = (double)vp[k]; s = fma(v[k], v[k], s); }
  double den = fmax(sqrt(s), 1e-12);
  double gg = (double)g[gid];
  double* row = wn + ((size_t)i * DD + d) * KK;
  float* frow = wnf + ((size_t)i * DD + d) * KP;
#pragma unroll
  for (int k = 0; k < CD; k++) {
    double wv = gg * v[k] / den;
    row[k] = wv;
    frow[k] = (float)wv;
  }
  row[CD] = (double)bp[gid];
  frow[CD] = bp[gid];
  frow[9] = 0.0f; frow[10] = 0.0f; frow[11] = 0.0f;
}

__global__ void k_q(const float* __restrict__ CBp, const float* __restrict__ bp,
                    const double* __restrict__ wn,
                    double* __restrict__ q, float* __restrict__ qf) {
  int wid = blockIdx.x * 4 + (threadIdx.x >> 6);
  int lane = threadIdx.x & 63;
  int i = wid / CS, c = wid % CS;
  const float* cb = CBp + (size_t)(i * CS + c) * CD;
  double cbv[CD];
#pragma unroll
  for (int k = 0; k < CD; k++) cbv[k] = (double)cb[k];
  const double* wnp = wn + (size_t)i * DD * KK;
  const float* bb = bp + (size_t)i * DD;
  double acc = 0.0;
#pragma unroll
  for (int j = 0; j < 8; j++) {
    int d = j * 64 + lane;
    double imp = (double)bb[d];
#pragma unroll
    for (int k = 0; k < CD; k++) imp = fma(cbv[k], wnp[(size_t)d * KK + k], imp);
    acc = fma(imp, imp, acc);
  }
#pragma unroll
  for (int o = 32; o; o >>= 1) acc += __shfl_xor(acc, o, 64);
  if (lane == 0) { q[wid] = acc; qf[wid] = (float)(0.5 * acc); }
}

__launch_bounds__(256, 2)
__global__ void k_main(const float* __restrict__ z, const float* __restrict__ CBp,
                       const double* __restrict__ wn, const float* __restrict__ wnf,
                       const double* __restrict__ qtab, const float* __restrict__ qftab,
                       float* __restrict__ out_zq, float* __restrict__ out_codes,
                       double* __restrict__ partials) {
  __shared__ __align__(16) float tile[DD * 17];   // 34816 B — holds z all kernel
  __shared__ double cbuf[4];

  const int tid = threadIdx.x, lane = tid & 63, w = tid >> 6;
  const int bb = blockIdx.x >> 7, tg = blockIdx.x & 127;
  const int t0 = tg * 16;
  const float* zb = z + (size_t)bb * DD * TT + t0;

  // ---- prologue: stage z (non-temporal, SINGLE read), transpose in LDS ----
#pragma unroll
  for (int m = 0; m < 8; m++) {
    int F = tid + m * 256, d = F >> 2, qq = F & 3;
    const vf4 v = __builtin_nontemporal_load((const vf4*)(zb + (size_t)d * TT + qq * 4));
    tile[d * 17 + qq * 4 + 0] = v.x; tile[d * 17 + qq * 4 + 1] = v.y;
    tile[d * 17 + qq * 4 + 2] = v.z; tile[d * 17 + qq * 4 + 3] = v.w;
  }
  __syncthreads();

  double res[4][8], ns2[4];
#pragma unroll
  for (int r = 0; r < 4; r++) {
    double s = 0.0;
#pragma unroll
    for (int j = 0; j < 8; j++) {
      res[r][j] = (double)tile[(j * 64 + lane) * 17 + (w * 4 + r)];
      s = fma(res[r][j], res[r][j], s);
    }
    ns2[r] = s;
  }
#pragma unroll
  for (int o = 32; o; o >>= 1)
#pragma unroll
    for (int r = 0; r < 4; r++) ns2[r] += __shfl_xor(ns2[r], o, 64);

  double commit = 0.0;

  for (int i = 0; i < NCB; i++) {
    const float* wfp = wnf + (size_t)i * DD * KP;
    const float* cbbase = CBp + (size_t)i * CS * CD;
    const float* qfb = qftab + i * CS;
    const double* qb = qtab + i * CS;

    // ---- phase 1: pf[r][k] = -(res . [Wn|b]) in f32, one pass, 4 rows ----
    float pf[4][KK];
#pragma unroll
    for (int r = 0; r < 4; r++)
#pragma unroll
      for (int k = 0; k < KK; k++) pf[r][k] = 0.0f;
#pragma unroll
    for (int j = 0; j < 8; j++) {
      const float* row = wfp + (size_t)(j * 64 + lane) * KP;
      const float4 w0 = *(const float4*)(row);
      const float4 w1 = *(const float4*)(row + 4);
      const float  w8 = row[8];
      float rv[4];
#pragma unroll
      for (int r = 0; r < 4; r++) rv[r] = -(float)res[r][j];
#pragma unroll
      for (int r = 0; r < 4; r++) {
        pf[r][0] = fmaf(rv[r], w0.x, pf[r][0]);
        pf[r][1] = fmaf(rv[r], w0.y, pf[r][1]);
        pf[r][2] = fmaf(rv[r], w0.z, pf[r][2]);
        pf[r][3] = fmaf(rv[r], w0.w, pf[r][3]);
        pf[r][4] = fmaf(rv[r], w1.x, pf[r][4]);
        pf[r][5] = fmaf(rv[r], w1.y, pf[r][5]);
        pf[r][6] = fmaf(rv[r], w1.z, pf[r][6]);
        pf[r][7] = fmaf(rv[r], w1.w, pf[r][7]);
        pf[r][8] = fmaf(rv[r], w8,   pf[r][8]);
      }
    }
#pragma unroll
    for (int o = 32; o; o >>= 1)
#pragma unroll
      for (int r = 0; r < 4; r++)
#pragma unroll
        for (int k = 0; k < KK; k++) pf[r][k] += __shfl_xor(pf[r][k], o, 64);

    // ---- phase 2: f32 argmin, one CB sweep, split even/odd chains ----
    float s1a[4], s2a[4], s1b[4], s2b[4];
    int   c1a[4], c1b[4];
#pragma unroll
    for (int r = 0; r < 4; r++) {
      s1a[r] = s2a[r] = s1b[r] = s2b[r] = 3.4e38f;
      c1a[r] = c1b[r] = 0;
    }
#pragma unroll 4
    for (int m = 0; m < 16; m += 2) {
#pragma unroll
      for (int h = 0; h < 2; h++) {
        int c = (m + h) * 64 + lane;
        const float4 c0 = *(const float4*)(cbbase + (size_t)c * CD);
        const float4 cx = *(const float4*)(cbbase + (size_t)c * CD + 4);
        float qv = qfb[c];
#pragma unroll
        for (int r = 0; r < 4; r++) {
          float s = qv;
          s = fmaf(c0.x, pf[r][0], s); s = fmaf(c0.y, pf[r][1], s);
          s = fmaf(c0.z, pf[r][2], s); s = fmaf(c0.w, pf[r][3], s);
          s = fmaf(cx.x, pf[r][4], s); s = fmaf(cx.y, pf[r][5], s);
          s = fmaf(cx.z, pf[r][6], s); s = fmaf(cx.w, pf[r][7], s);
          if (h == 0) {
            if (s < s1a[r]) { s2a[r] = s1a[r]; s1a[r] = s; c1a[r] = c; }
            else            { s2a[r] = fminf(s2a[r], s); }
          } else {
            if (s < s1b[r]) { s2b[r] = s1b[r]; s1b[r] = s; c1b[r] = c; }
            else            { s2b[r] = fminf(s2b[r], s); }
          }
        }
      }
    }
    float s1[4], s2[4]; int c1[4];
#pragma unroll
    for (int r = 0; r < 4; r++) {
      if (s1a[r] < s1b[r] || (s1a[r] == s1b[r] && c1a[r] < c1b[r])) {
        s1[r] = s1a[r]; c1[r] = c1a[r]; s2[r] = fminf(s2a[r], s1b[r]);
      } else {
        s1[r] = s1b[r]; c1[r] = c1b[r]; s2[r] = fminf(s2b[r], s1a[r]);
      }
    }
#pragma unroll
    for (int o = 32; o; o >>= 1) {
#pragma unroll
      for (int r = 0; r < 4; r++) {
        float os1 = __shfl_xor(s1[r], o, 64);
        int   oc1 = __shfl_xor(c1[r], o, 64);
        float os2 = __shfl_xor(s2[r], o, 64);
        float hi = fmaxf(s1[r], os1);
        s2[r] = fminf(fminf(s2[r], os2), hi);
        if (os1 < s1[r] || (os1 == s1[r] && oc1 < c1[r])) { s1[r] = os1; c1[r] = oc1; }
      }
    }

    // ---- per-row: rare exact-f64 fallback (global f64 Wn), scalars ----
    double Ap[4], Cm[4];
    float cbf[4][8];
#pragma unroll
    for (int r = 0; r < 4; r++) {
      if (s2[r] - s1[r] < GAPTHR) {   // wave-uniform, rare
        double pd[KK];
#pragma unroll
        for (int k = 0; k < KK; k++) pd[k] = 0.0;
#pragma unroll
        for (int j = 0; j < 8; j++) {
          const double* wrow = wn + ((size_t)i * DD + j * 64 + lane) * KK;
          double rv = res[r][j];
#pragma unroll
          for (int k = 0; k < KK; k++) pd[k] = fma(rv, wrow[k], pd[k]);
        }
#pragma unroll
        for (int o = 32; o; o >>= 1)
#pragma unroll
          for (int k = 0; k < KK; k++) pd[k] += __shfl_xor(pd[k], o, 64);
        double pm2[8];
#pragma unroll
        for (int k = 0; k < 8; k++) pm2[k] = -2.0 * pd[k];
        double bs = 1e300; int bc = 0;
#pragma unroll 4
        for (int m = 0; m < 16; m++) {
          int c = m * 64 + lane;
          const float* cb2 = cbbase + (size_t)c * CD;
          double s = qb[c];
#pragma unroll
          for (int k = 0; k < 8; k++) s = fma((double)cb2[k], pm2[k], s);
          if (s < bs) { bs = s; bc = c; }
        }
#pragma unroll
        for (int o = 32; o; o >>= 1) {
          double obs = __shfl_xor(bs, o, 64);
          int    obc = __shfl_xor(bc, o, 64);
          if (obs < bs || (obs == bs && obc < bc)) { bs = obs; bc = obc; }
        }
        c1[r] = bc;
      }
      int cu = __builtin_amdgcn_readfirstlane(c1[r]);
      const float* cbr = cbbase + (size_t)cu * CD;
      double pzn = (double)pf[r][8];
#pragma unroll
      for (int k = 0; k < 8; k++) {
        float cf = cbr[k];
        cbf[r][k] = cf;
        pzn = fma((double)cf, (double)pf[r][k], pzn);
      }
      double pz = -pzn;
      double nt2 = qb[cu];
      double n2 = ns2[r];
      // rotation scalars in f32 (A/C need only ~1e-7 rel; decisions already made)
      float n2f = (float)n2, nt2f = (float)nt2, pzf = (float)pz;
      float rnsf = (n2f  > 1e-12f) ? rsqrtf(n2f)  : 1e6f;
      float rntf = (nt2f > 1e-12f) ? rsqrtf(nt2f) : 1e6f;
      float sntf = nt2f * rntf;               // sqrt(nt2)
      float wn2f = n2f * rnsf * rnsf + 2.0f * pzf * rnsf * rntf + nt2f * rntf * rntf;
      float rdwf = (wn2f > 1e-12f) ? rsqrtf(wn2f) : 1e6f;
      float euf = n2f * rnsf;
      float ewf = (n2f * rnsf + pzf * rntf) * rdwf;
      float scalef = sntf * rnsf;
      float Af = scalef * (1.0f - 2.0f * ewf * rdwf * rnsf);
      float Cf = scalef * rntf * 2.0f * (euf - ewf * rdwf);
      commit += n2 - 2.0 * pz + nt2;
      double ap = 1.0 - (double)Af;
      double C  = (double)Cf;
      Ap[r] = ap; Cm[r] = C;
      ns2[r] = ap * ap * n2 - 2.0 * ap * C * pz + C * C * nt2;
      if (lane == 0)
        out_codes[((size_t)bb * NCB + i) * TT + t0 + w * 4 + r] = (float)cu;
    }

    // ---- phase 3: res' = Ap*res - Cm*(b + Wn.cb), f32 imp, one pass ----
#pragma unroll
    for (int j = 0; j < 8; j++) {
      const float* row = wfp + (size_t)(j * 64 + lane) * KP;
      const float4 w0 = *(const float4*)(row);
      const float4 w1 = *(const float4*)(row + 4);
      const float  w8 = row[8];
#pragma unroll
      for (int r = 0; r < 4; r++) {
        float impf = w8;
        impf = fmaf(cbf[r][0], w0.x, impf);
        impf = fmaf(cbf[r][1], w0.y, impf);
        impf = fmaf(cbf[r][2], w0.z, impf);
        impf = fmaf(cbf[r][3], w0.w, impf);
        impf = fmaf(cbf[r][4], w1.x, impf);
        impf = fmaf(cbf[r][5], w1.y, impf);
        impf = fmaf(cbf[r][6], w1.z, impf);
        impf = fmaf(cbf[r][7], w1.w, impf);
        res[r][j] = Ap[r] * res[r][j] - Cm[r] * (double)impf;
      }
    }
  }

  // ---- commit: wave-uniform already; lane 0 holds the wave total ----
  if (lane == 0) cbuf[w] = commit;

  // ---- z_q = z - res : tile STILL holds z (untouched by main loop).
  //      Each thread updates exactly the slots it alone read at res-init
  //      (unique ownership -> no race); one barrier; nt-store coalesced. ----
#pragma unroll
  for (int r = 0; r < 4; r++)
#pragma unroll
    for (int j = 0; j < 8; j++) {
      int idx = (j * 64 + lane) * 17 + (w * 4 + r);
      tile[idx] = tile[idx] - (float)res[r][j];
    }
  __syncthreads();   // all slots updated; covers cbuf too
#pragma unroll
  for (int m = 0; m < 8; m++) {
    int F = tid + m * 256, d = F >> 2, qq = F & 3;
    vf4 o;
    o.x = tile[d * 17 + qq * 4 + 0];
    o.y = tile[d * 17 + qq * 4 + 1];
    o.z = tile[d * 17 + qq * 4 + 2];
    o.w = tile[d * 17 + qq * 4 + 3];
    __builtin_nontemporal_store(o, (vf4*)(out_zq + ((size_t)bb * DD + d) * TT + t0 + qq * 4));
  }
  if (tid == 0)
    partials[blockIdx.x] = cbuf[0] + cbuf[1] + cbuf[2] + cbuf[3];
}

__global__ void k_fin(const double* __restrict__ partials, float* __restrict__ outc) {
  __shared__ double sb[4];
  int tid = threadIdx.x, lane = tid & 63, w = tid >> 6;
  double s = 0.0;
#pragma unroll
  for (int m = 0; m < NBLK / 256; m++) s += partials[tid + m * 256];
#pragma unroll
  for (int o = 32; o; o >>= 1) s += __shfl_xor(s, o, 64);
  if (lane == 0) sb[w] = s;
  __syncthreads();
  if (tid == 0) {
    double tot = sb[0] + sb[1] + sb[2] + sb[3];
    outc[0] = (float)(tot * 1.25 / (double)((size_t)NB * TT * DD));
  }
}

extern "C" void kernel_launch(void* const* d_in, const int* in_sizes, int n_in,
                              void* d_out, int out_size, void* d_ws, size_t ws_size,
                              hipStream_t stream) {
  const float* z  = (const float*)d_in[0];
  const float* V  = (const float*)d_in[1];
  const float* g  = (const float*)d_in[2];
  const float* b  = (const float*)d_in[3];
  const float* CB = (const float*)d_in[4];
  float* out = (float*)d_out;

  double* parts = (double*)d_ws;
  double* wn  = (double*)((char*)d_ws + WS_WN_OFF);
  float*  wnf = (float*)((char*)d_ws + WS_WNF_OFF);
  double* q   = (double*)((char*)d_ws + WS_Q_OFF);
  float*  qf  = (float*)((char*)d_ws + WS_QF_OFF);

  hipLaunchKernelGGL(k_wn, dim3((NCB * DD + 255) / 256), dim3(256), 0, stream,
                     V, g, b, wn, wnf);
  hipLaunchKernelGGL(k_q, dim3((NCB * CS) / 4), dim3(256), 0, stream, CB, b, wn, q, qf);
  hipLaunchKernelGGL(k_main, dim3(NBLK), dim3(256), 0, stream,
                     z, CB, wn, wnf, q, qf,
                     out, out + (size_t)NB * DD * TT, parts);
  hipLaunchKernelGGL(k_fin, dim3(1), dim3(256), 0, stream,
                     parts, out + (size_t)NB * DD * TT + (size_t)NB * NCB * TT);
}